// Round 3
// baseline (601.435 us; speedup 1.0000x reference)
//
#include <hip/hip_runtime.h>
#include <stdint.h>

#define BATCH 64
#define NQ 300
#define NCH 84            // 4 + 80
#define KTOP 150
#define NTOT (NQ * NCH)   // 25200
#define KDIM 1200
#define KCH  600          // K chunk (2 chunks)
#define HW 640
#define PF 8              // W prefetch depth (KCH % PF == 0)

// ws layout (bytes), fp64 pipeline (identical to proven baseline):
//   At : [0, 614400)                    1200*64 double
//   Y  : [614400, 26419200)             2 * 64*25200 double (K-chunk partials)
//   sc : [26419200, 26572800)           64*300 double
//   cid: [26572800, 26649600)           64*300 int
#define WS_Y   614400
#define WS_SC  26419200
#define WS_CID 26572800

// ---------------- Kernel 1: 32x32 average pool (exact int sum) --------------
// x: (64,3,640,640) int32  ->  At: (1200, 64) double   (A transposed)
// flat k = c_new*400 + ph*20 + pw, where c_new = 2 - c_in  (BGR flip)
__global__ __launch_bounds__(256) void pool_kernel(const int* __restrict__ x,
                                                   double* __restrict__ At) {
  int wave = threadIdx.x >> 6;
  int lane = threadIdx.x & 63;
  int cell = blockIdx.x * 4 + wave;            // 0 .. 76799
  int b   = cell / 1200;
  int rem = cell - b * 1200;
  int cin = rem / 400;
  int pp  = rem - cin * 400;                   // ph*20 + pw
  int ph = pp / 20, pw = pp - ph * 20;
  const int* base = x + (((b * 3 + cin) * HW) + ph * 32) * HW + pw * 32;
  int r  = lane >> 1;                          // 0..31 (row in block)
  int c0 = (lane & 1) * 16;                    // 0 or 16 (col in block)
  const int4* p = (const int4*)(base + r * HW + c0);
  int4 v0 = p[0], v1 = p[1], v2 = p[2], v3 = p[3];
  int s = v0.x + v0.y + v0.z + v0.w + v1.x + v1.y + v1.z + v1.w
        + v2.x + v2.y + v2.z + v2.w + v3.x + v3.y + v3.z + v3.w;
  #pragma unroll
  for (int off = 32; off > 0; off >>= 1) s += __shfl_down(s, off);
  if (lane == 0) {
    int kout = (2 - cin) * 400 + pp;
    At[kout * 64 + b] = (double)s * (1.0 / 261120.0);  // / (255*1024)
  }
}

// ---------------- Kernel 2: fp64 GEMM, W-read-once, 2-chunk split-K ---------
// At: (1200,64) double   W: (1200,25200) float   Y: (2, 64, 25200) double
// blockIdx.y = K chunk. Block covers ALL 64 batch rows x 64 cols; each of the
// 4 waves owns 16 rows (wave-uniform row0 -> A reads are scalar loads), each
// lane one output column. Each W element is now read by exactly ONE block ->
// W HBM traffic 121 MB (was 242 MB with 2 row-groups). Per-output fma order
// (k ascending within chunk, chunk0+chunk1 downstream) is BIT-IDENTICAL to
// the proven passing baseline; only the wave->row mapping changed.
// 394*2 blocks * 4 waves = 3.08 waves/SIMD; each PF-group issues ~512 cyc of
// fp64 FMA per wave vs one ~500 cyc HBM round-trip -> latency covered.
__global__ __launch_bounds__(256) void gemm_kernel(const double* __restrict__ At,
                                                   const float* __restrict__ W,
                                                   double* __restrict__ Y) {
  int wave  = threadIdx.x >> 6;
  int lane  = threadIdx.x & 63;
  int chunk = blockIdx.y;
  int row0  = __builtin_amdgcn_readfirstlane((int)(wave * 16));
  int n  = blockIdx.x * 64 + lane;
  int nl = n < NTOT ? n : NTOT - 1;            // clamp (no divergent load)
  const double* Ap = At + (size_t)chunk * KCH * 64 + row0;   // Ap[k*64 + i]
  const float*  Wp = W + (size_t)chunk * KCH * NTOT + nl;
  double acc[16];
  #pragma unroll
  for (int i = 0; i < 16; ++i) acc[i] = 0.0;
  float w[PF];
  #pragma unroll
  for (int u = 0; u < PF; ++u) w[u] = Wp[(size_t)u * NTOT];
  #pragma unroll 1
  for (int k0 = 0; k0 < KCH; k0 += PF) {
    int kn = (k0 + PF == KCH) ? 0 : k0 + PF;   // last prefetch wraps (unused)
    float wn[PF];
    #pragma unroll
    for (int u = 0; u < PF; ++u) wn[u] = Wp[(size_t)(kn + u) * NTOT];
    #pragma unroll
    for (int u = 0; u < PF; ++u) {
      double wd = (double)w[u];
      #pragma unroll
      for (int i = 0; i < 16; ++i)
        acc[i] = fma(Ap[(size_t)(k0 + u) * 64 + i], wd, acc[i]);
    }
    #pragma unroll
    for (int u = 0; u < PF; ++u) w[u] = wn[u];
  }
  if (n < NTOT) {
    double* Yp = Y + ((size_t)chunk * BATCH + row0) * NTOT + n;
    #pragma unroll
    for (int i = 0; i < 16; ++i) Yp[(size_t)i * NTOT] = acc[i];
  }
}

// ---------------- Kernel 3a: per-query argmax over 80 classes ---------------
// One wave per (b,q). Sums the two K-chunk partials (fixed order), then
// shuffle max-reduce with tie -> smaller class index (numpy argmax order).
__global__ __launch_bounds__(256) void argmax_kernel(const double* __restrict__ Y,
                                                     double* __restrict__ sc,
                                                     int* __restrict__ cid) {
  int wave = threadIdx.x >> 6;
  int lane = threadIdx.x & 63;
  int task = blockIdx.x * 4 + wave;            // 0 .. 19199
  int b = task / NQ;
  int q = task - b * NQ;
  const double* y0 = Y + (size_t)b * NTOT + q * NCH;
  const double* y1 = y0 + (size_t)BATCH * NTOT;
  double best = y0[4 + lane] + y1[4 + lane];
  int    cls  = lane;
  if (lane < 16) {
    double v2 = y0[68 + lane] + y1[68 + lane];
    if (v2 > best) { best = v2; cls = 64 + lane; }   // strict > : lower idx wins ties
  }
  #pragma unroll
  for (int off = 32; off > 0; off >>= 1) {
    double ob = __shfl_down(best, off);
    int    oc = __shfl_down(cls, off);
    if (ob > best || (ob == best && oc < cls)) { best = ob; cls = oc; }
  }
  if (lane == 0) { sc[task] = best; cid[task] = cls; }
}

// ---------------- Kernel 3b: stable top-150 by rank selection ---------------
// One block per batch; scores in LDS; exact rank under (score desc, q asc);
// only the 150 winners touch global Y (both partials) for their boxes.
__global__ __launch_bounds__(256) void select_kernel(const double* __restrict__ Y,
                                                     const double* __restrict__ sc,
                                                     const int* __restrict__ cid,
                                                     float* __restrict__ out) {
  __shared__ double ssc[NQ];
  __shared__ int    scid[NQ];
  int b = blockIdx.x;
  int t = threadIdx.x;
  for (int q = t; q < NQ; q += 256) {
    ssc[q]  = sc[b * NQ + q];
    scid[q] = cid[b * NQ + q];
  }
  __syncthreads();
  for (int q = t; q < NQ; q += 256) {
    double s = ssc[q];
    int rank = 0;
    for (int j = 0; j < NQ; ++j) {
      double sj = ssc[j];
      rank += (sj > s) || (sj == s && j < q);
    }
    if (rank < KTOP) {
      const double* r0 = Y + (size_t)b * NTOT + q * NCH;
      const double* r1 = r0 + (size_t)BATCH * NTOT;
      float* o = out + ((size_t)b * KTOP + rank) * 6;
      o[0] = (float)(r0[0] + r1[0]);
      o[1] = (float)(r0[1] + r1[1]);
      o[2] = (float)(r0[2] + r1[2]);
      o[3] = (float)(r0[3] + r1[3]);
      o[4] = (float)s;
      o[5] = (float)scid[q];
    }
  }
}

extern "C" void kernel_launch(void* const* d_in, const int* in_sizes, int n_in,
                              void* d_out, int out_size, void* d_ws, size_t ws_size,
                              hipStream_t stream) {
  const int*   x = (const int*)d_in[0];
  const float* W = (const float*)d_in[1];
  double* At  = (double*)d_ws;
  double* Y   = (double*)((char*)d_ws + WS_Y);
  double* sc  = (double*)((char*)d_ws + WS_SC);
  int*    cid = (int*)((char*)d_ws + WS_CID);
  pool_kernel<<<dim3(19200), dim3(256), 0, stream>>>(x, At);
  gemm_kernel<<<dim3(394, 2), dim3(256), 0, stream>>>(At, W, Y);
  argmax_kernel<<<dim3(4800), dim3(256), 0, stream>>>(Y, sc, cid);
  select_kernel<<<dim3(64), dim3(256), 0, stream>>>(Y, sc, cid, (float*)d_out);
}

// Round 4
// 597.606 us; speedup vs baseline: 1.0064x; 1.0064x over previous
//
#include <hip/hip_runtime.h>
#include <stdint.h>

#define BATCH 64
#define NQ 300
#define NCH 84            // 4 + 80
#define KTOP 150
#define NTOT (NQ * NCH)   // 25200
#define KDIM 1200
#define NCHUNK 4
#define KCH 300           // K per chunk (4 chunks)
#define HW 640
#define PF 6              // W prefetch depth (KCH % PF == 0), kept small for VGPR<=64

// ws layout (bytes), fp64 pipeline, 4 K-chunk partials:
//   At : [0, 614400)                    1200*64 double
//   Y  : [614400, 52224000)             4 * 64*25200 double (K-chunk partials)
//   sc : [52224000, 52377600)           64*300 double
//   cid: [52377600, 52454400)           64*300 int
#define WS_Y   614400
#define WS_SC  52224000
#define WS_CID 52377600

// ---------------- Kernel 1: 32x32 average pool (exact int sum) --------------
// x: (64,3,640,640) int32  ->  At: (1200, 64) double   (A transposed)
// flat k = c_new*400 + ph*20 + pw, where c_new = 2 - c_in  (BGR flip)
__global__ __launch_bounds__(256) void pool_kernel(const int* __restrict__ x,
                                                   double* __restrict__ At) {
  int wave = threadIdx.x >> 6;
  int lane = threadIdx.x & 63;
  int cell = blockIdx.x * 4 + wave;            // 0 .. 76799
  int b   = cell / 1200;
  int rem = cell - b * 1200;
  int cin = rem / 400;
  int pp  = rem - cin * 400;                   // ph*20 + pw
  int ph = pp / 20, pw = pp - ph * 20;
  const int* base = x + (((b * 3 + cin) * HW) + ph * 32) * HW + pw * 32;
  int r  = lane >> 1;                          // 0..31 (row in block)
  int c0 = (lane & 1) * 16;                    // 0 or 16 (col in block)
  const int4* p = (const int4*)(base + r * HW + c0);
  int4 v0 = p[0], v1 = p[1], v2 = p[2], v3 = p[3];
  int s = v0.x + v0.y + v0.z + v0.w + v1.x + v1.y + v1.z + v1.w
        + v2.x + v2.y + v2.z + v2.w + v3.x + v3.y + v3.z + v3.w;
  #pragma unroll
  for (int off = 32; off > 0; off >>= 1) s += __shfl_down(s, off);
  if (lane == 0) {
    int kout = (2 - cin) * 400 + pp;
    At[kout * 64 + b] = (double)s * (1.0 / 261120.0);  // / (255*1024)
  }
}

// ---------------- Kernel 2: fp64 GEMM, W-read-once, high occupancy ----------
// At: (1200,64) double   W: (1200,25200) float   Y: (4, 64, 25200) double
// blockIdx.y = K chunk (K=300 each). 512-thread block = 8 waves x 8 rows
// = all 64 batch rows (W element read by exactly ONE block -> 121 MB), each
// lane one output column. row0 wave-uniform -> A reads are scalar loads.
// Grid 394x4 * 8 waves = 12608 waves = 12.3/SIMD launched; fp64 acc[8]
// (16 VGPR) + PF=6 prefetch keeps VGPR low so ~8 waves/SIMD stay resident —
// round-3 A/B showed this GEMM is latency-bound and occupancy-sensitive.
// fp64 4-chunk re-association noise ~1e-15 << decision margins ~1e-6.
__global__ __launch_bounds__(512) void gemm_kernel(const double* __restrict__ At,
                                                   const float* __restrict__ W,
                                                   double* __restrict__ Y) {
  int wave  = threadIdx.x >> 6;
  int lane  = threadIdx.x & 63;
  int chunk = blockIdx.y;
  int row0  = __builtin_amdgcn_readfirstlane((int)(wave * 8));
  int n  = blockIdx.x * 64 + lane;
  int nl = n < NTOT ? n : NTOT - 1;            // clamp (no divergent load)
  const double* Ap = At + (size_t)chunk * KCH * 64 + row0;   // Ap[k*64 + i]
  const float*  Wp = W + (size_t)chunk * KCH * NTOT + nl;
  double acc[8];
  #pragma unroll
  for (int i = 0; i < 8; ++i) acc[i] = 0.0;
  float w[PF];
  #pragma unroll
  for (int u = 0; u < PF; ++u) w[u] = Wp[(size_t)u * NTOT];
  #pragma unroll 1
  for (int k0 = 0; k0 < KCH; k0 += PF) {
    int kn = (k0 + PF == KCH) ? 0 : k0 + PF;   // last prefetch wraps (unused)
    float wn[PF];
    #pragma unroll
    for (int u = 0; u < PF; ++u) wn[u] = Wp[(size_t)(kn + u) * NTOT];
    #pragma unroll
    for (int u = 0; u < PF; ++u) {
      double wd = (double)w[u];
      #pragma unroll
      for (int i = 0; i < 8; ++i)
        acc[i] = fma(Ap[(size_t)(k0 + u) * 64 + i], wd, acc[i]);
    }
    #pragma unroll
    for (int u = 0; u < PF; ++u) w[u] = wn[u];
  }
  if (n < NTOT) {
    double* Yp = Y + ((size_t)chunk * BATCH + row0) * NTOT + n;
    #pragma unroll
    for (int i = 0; i < 8; ++i) Yp[(size_t)i * NTOT] = acc[i];
  }
}

// ---------------- Kernel 3a: per-query argmax over 80 classes ---------------
// One wave per (b,q). Sums the four K-chunk partials in a FIXED order
// (((c0+c1)+c2)+c3), then shuffle max-reduce, tie -> smaller class index.
__global__ __launch_bounds__(256) void argmax_kernel(const double* __restrict__ Y,
                                                     double* __restrict__ sc,
                                                     int* __restrict__ cid) {
  int wave = threadIdx.x >> 6;
  int lane = threadIdx.x & 63;
  int task = blockIdx.x * 4 + wave;            // 0 .. 19199
  int b = task / NQ;
  int q = task - b * NQ;
  const double* y = Y + (size_t)b * NTOT + q * NCH;
  const size_t P = (size_t)BATCH * NTOT;
  double best = ((y[4 + lane] + y[P + 4 + lane]) + y[2 * P + 4 + lane]) + y[3 * P + 4 + lane];
  int    cls  = lane;
  if (lane < 16) {
    double v2 = ((y[68 + lane] + y[P + 68 + lane]) + y[2 * P + 68 + lane]) + y[3 * P + 68 + lane];
    if (v2 > best) { best = v2; cls = 64 + lane; }   // strict > : lower idx wins ties
  }
  #pragma unroll
  for (int off = 32; off > 0; off >>= 1) {
    double ob = __shfl_down(best, off);
    int    oc = __shfl_down(cls, off);
    if (ob > best || (ob == best && oc < cls)) { best = ob; cls = oc; }
  }
  if (lane == 0) { sc[task] = best; cid[task] = cls; }
}

// ---------------- Kernel 3b: stable top-150 by rank selection ---------------
// One block per batch; scores in LDS; exact rank under (score desc, q asc);
// only the 150 winners touch global Y (all 4 partials) for their boxes.
__global__ __launch_bounds__(256) void select_kernel(const double* __restrict__ Y,
                                                     const double* __restrict__ sc,
                                                     const int* __restrict__ cid,
                                                     float* __restrict__ out) {
  __shared__ double ssc[NQ];
  __shared__ int    scid[NQ];
  int b = blockIdx.x;
  int t = threadIdx.x;
  for (int q = t; q < NQ; q += 256) {
    ssc[q]  = sc[b * NQ + q];
    scid[q] = cid[b * NQ + q];
  }
  __syncthreads();
  const size_t P = (size_t)BATCH * NTOT;
  for (int q = t; q < NQ; q += 256) {
    double s = ssc[q];
    int rank = 0;
    for (int j = 0; j < NQ; ++j) {
      double sj = ssc[j];
      rank += (sj > s) || (sj == s && j < q);
    }
    if (rank < KTOP) {
      const double* r0 = Y + (size_t)b * NTOT + q * NCH;
      float* o = out + ((size_t)b * KTOP + rank) * 6;
      o[0] = (float)(((r0[0] + r0[P + 0]) + r0[2 * P + 0]) + r0[3 * P + 0]);
      o[1] = (float)(((r0[1] + r0[P + 1]) + r0[2 * P + 1]) + r0[3 * P + 1]);
      o[2] = (float)(((r0[2] + r0[P + 2]) + r0[2 * P + 2]) + r0[3 * P + 2]);
      o[3] = (float)(((r0[3] + r0[P + 3]) + r0[2 * P + 3]) + r0[3 * P + 3]);
      o[4] = (float)s;
      o[5] = (float)scid[q];
    }
  }
}

extern "C" void kernel_launch(void* const* d_in, const int* in_sizes, int n_in,
                              void* d_out, int out_size, void* d_ws, size_t ws_size,
                              hipStream_t stream) {
  const int*   x = (const int*)d_in[0];
  const float* W = (const float*)d_in[1];
  double* At  = (double*)d_ws;
  double* Y   = (double*)((char*)d_ws + WS_Y);
  double* sc  = (double*)((char*)d_ws + WS_SC);
  int*    cid = (int*)((char*)d_ws + WS_CID);
  pool_kernel<<<dim3(19200), dim3(256), 0, stream>>>(x, At);
  gemm_kernel<<<dim3(394, NCHUNK), dim3(512), 0, stream>>>(At, W, Y);
  argmax_kernel<<<dim3(4800), dim3(256), 0, stream>>>(Y, sc, cid);
  select_kernel<<<dim3(64), dim3(256), 0, stream>>>(Y, sc, cid, (float*)d_out);
}

// Round 5
// 592.747 us; speedup vs baseline: 1.0147x; 1.0082x over previous
//
#include <hip/hip_runtime.h>
#include <stdint.h>

#define BATCH 64
#define NQ 300
#define NCH 84            // 4 + 80
#define KTOP 150
#define NTOT (NQ * NCH)   // 25200
#define KDIM 1200
#define NCHUNK 4
#define KCH 300           // K per chunk (4 chunks)
#define HW 640
#define PF 6              // W prefetch depth (KCH % PF == 0)

// ws layout (bytes), fp64 pipeline, 4 K-chunk partials:
//   At : [0, 614400)                    1200*64 double
//   Y  : [614400, 52224000)             4 * 64*25200 double (K-chunk partials)
//   sc : [52224000, 52377600)           64*300 double
//   cid: [52377600, 52454400)           64*300 int
#define WS_Y   614400
#define WS_SC  52224000
#define WS_CID 52377600

// ---------------- Kernel 1: 32x32 average pool (exact int sum) --------------
// x: (64,3,640,640) int32  ->  At: (1200, 64) double   (A transposed)
// flat k = c_new*400 + ph*20 + pw, where c_new = 2 - c_in  (BGR flip)
__global__ __launch_bounds__(256) void pool_kernel(const int* __restrict__ x,
                                                   double* __restrict__ At) {
  int wave = threadIdx.x >> 6;
  int lane = threadIdx.x & 63;
  int cell = blockIdx.x * 4 + wave;            // 0 .. 76799
  int b   = cell / 1200;
  int rem = cell - b * 1200;
  int cin = rem / 400;
  int pp  = rem - cin * 400;                   // ph*20 + pw
  int ph = pp / 20, pw = pp - ph * 20;
  const int* base = x + (((b * 3 + cin) * HW) + ph * 32) * HW + pw * 32;
  int r  = lane >> 1;                          // 0..31 (row in block)
  int c0 = (lane & 1) * 16;                    // 0 or 16 (col in block)
  const int4* p = (const int4*)(base + r * HW + c0);
  int4 v0 = p[0], v1 = p[1], v2 = p[2], v3 = p[3];
  int s = v0.x + v0.y + v0.z + v0.w + v1.x + v1.y + v1.z + v1.w
        + v2.x + v2.y + v2.z + v2.w + v3.x + v3.y + v3.z + v3.w;
  #pragma unroll
  for (int off = 32; off > 0; off >>= 1) s += __shfl_down(s, off);
  if (lane == 0) {
    int kout = (2 - cin) * 400 + pp;
    At[kout * 64 + b] = (double)s * (1.0 / 261120.0);  // / (255*1024)
  }
}

// ---------------- Kernel 2: fp64 GEMM, issue-slot-minimized -----------------
// At: (1200,64) double   W: (1200,25200) float   Y: (4, 64, 25200) double
// Rounds 3/4 A/B: occupancy and W-traffic changes were all flat -> GEMM is
// ISSUE-bound. This version cuts issue slots per FLOP ~40%:
//   - each lane owns TWO adjacent output columns (n0+2*lane, +1): W is one
//     float2 load per k, Y stores are double2, per-FLOP A-issue halves;
//   - A loaded as double2 (8 rows = 4 loads instead of 8 scalar doubles).
// A-load instrs: 30.2M -> 7.6M; FMA issue (30.2M x 4cyc ~ 49 us) unchanged —
// that is the fp64 floor. Per-output fma order (k ascending within chunk,
// fixed 4-partial order downstream) is BIT-IDENTICAL to the passing round-4
// kernel. 197x4 blocks x 8 waves = 6304 waves = 6.2/SIMD; VGPR ~75.
__global__ __launch_bounds__(512) void gemm_kernel(const double* __restrict__ At,
                                                   const float* __restrict__ W,
                                                   double* __restrict__ Y) {
  int wave  = threadIdx.x >> 6;
  int lane  = threadIdx.x & 63;
  int chunk = blockIdx.y;
  int row0  = __builtin_amdgcn_readfirstlane((int)(wave * 8));
  int n  = blockIdx.x * 128 + 2 * lane;        // first of this lane's 2 cols
  int nl = n < NTOT - 1 ? n : NTOT - 2;        // clamp (even, no divergent load)
  const double2* Ap = (const double2*)(At + (size_t)chunk * KCH * 64 + row0);
  const float*   Wp = W + (size_t)chunk * KCH * NTOT + nl;
  double acc0[8], acc1[8];
  #pragma unroll
  for (int i = 0; i < 8; ++i) { acc0[i] = 0.0; acc1[i] = 0.0; }
  float2 w[PF];
  #pragma unroll
  for (int u = 0; u < PF; ++u) w[u] = *(const float2*)(Wp + (size_t)u * NTOT);
  #pragma unroll 1
  for (int k0 = 0; k0 < KCH; k0 += PF) {
    int kn = (k0 + PF == KCH) ? 0 : k0 + PF;   // last prefetch wraps (unused)
    float2 wn[PF];
    #pragma unroll
    for (int u = 0; u < PF; ++u) wn[u] = *(const float2*)(Wp + (size_t)(kn + u) * NTOT);
    #pragma unroll
    for (int u = 0; u < PF; ++u) {
      double wd0 = (double)w[u].x;
      double wd1 = (double)w[u].y;
      #pragma unroll
      for (int j = 0; j < 4; ++j) {
        double2 a = Ap[(size_t)(k0 + u) * 32 + j]; // rows row0+2j, row0+2j+1
        acc0[2 * j]     = fma(a.x, wd0, acc0[2 * j]);
        acc1[2 * j]     = fma(a.x, wd1, acc1[2 * j]);
        acc0[2 * j + 1] = fma(a.y, wd0, acc0[2 * j + 1]);
        acc1[2 * j + 1] = fma(a.y, wd1, acc1[2 * j + 1]);
      }
    }
    #pragma unroll
    for (int u = 0; u < PF; ++u) w[u] = wn[u];
  }
  if (n < NTOT) {                              // n even; n+1 in range too
    double* Yp = Y + ((size_t)chunk * BATCH + row0) * NTOT + n;
    #pragma unroll
    for (int i = 0; i < 8; ++i) {
      double2 o; o.x = acc0[i]; o.y = acc1[i];
      *(double2*)(Yp + (size_t)i * NTOT) = o;
    }
  }
}

// ---------------- Kernel 3a: per-query argmax over 80 classes ---------------
// One wave per (b,q). Sums the four K-chunk partials in a FIXED order
// (((c0+c1)+c2)+c3), then shuffle max-reduce, tie -> smaller class index.
__global__ __launch_bounds__(256) void argmax_kernel(const double* __restrict__ Y,
                                                     double* __restrict__ sc,
                                                     int* __restrict__ cid) {
  int wave = threadIdx.x >> 6;
  int lane = threadIdx.x & 63;
  int task = blockIdx.x * 4 + wave;            // 0 .. 19199
  int b = task / NQ;
  int q = task - b * NQ;
  const double* y = Y + (size_t)b * NTOT + q * NCH;
  const size_t P = (size_t)BATCH * NTOT;
  double best = ((y[4 + lane] + y[P + 4 + lane]) + y[2 * P + 4 + lane]) + y[3 * P + 4 + lane];
  int    cls  = lane;
  if (lane < 16) {
    double v2 = ((y[68 + lane] + y[P + 68 + lane]) + y[2 * P + 68 + lane]) + y[3 * P + 68 + lane];
    if (v2 > best) { best = v2; cls = 64 + lane; }   // strict > : lower idx wins ties
  }
  #pragma unroll
  for (int off = 32; off > 0; off >>= 1) {
    double ob = __shfl_down(best, off);
    int    oc = __shfl_down(cls, off);
    if (ob > best || (ob == best && oc < cls)) { best = ob; cls = oc; }
  }
  if (lane == 0) { sc[task] = best; cid[task] = cls; }
}

// ---------------- Kernel 3b: stable top-150 by rank selection ---------------
// One block per batch; scores in LDS; exact rank under (score desc, q asc);
// only the 150 winners touch global Y (all 4 partials) for their boxes.
__global__ __launch_bounds__(256) void select_kernel(const double* __restrict__ Y,
                                                     const double* __restrict__ sc,
                                                     const int* __restrict__ cid,
                                                     float* __restrict__ out) {
  __shared__ double ssc[NQ];
  __shared__ int    scid[NQ];
  int b = blockIdx.x;
  int t = threadIdx.x;
  for (int q = t; q < NQ; q += 256) {
    ssc[q]  = sc[b * NQ + q];
    scid[q] = cid[b * NQ + q];
  }
  __syncthreads();
  const size_t P = (size_t)BATCH * NTOT;
  for (int q = t; q < NQ; q += 256) {
    double s = ssc[q];
    int rank = 0;
    for (int j = 0; j < NQ; ++j) {
      double sj = ssc[j];
      rank += (sj > s) || (sj == s && j < q);
    }
    if (rank < KTOP) {
      const double* r0 = Y + (size_t)b * NTOT + q * NCH;
      float* o = out + ((size_t)b * KTOP + rank) * 6;
      o[0] = (float)(((r0[0] + r0[P + 0]) + r0[2 * P + 0]) + r0[3 * P + 0]);
      o[1] = (float)(((r0[1] + r0[P + 1]) + r0[2 * P + 1]) + r0[3 * P + 1]);
      o[2] = (float)(((r0[2] + r0[P + 2]) + r0[2 * P + 2]) + r0[3 * P + 2]);
      o[3] = (float)(((r0[3] + r0[P + 3]) + r0[2 * P + 3]) + r0[3 * P + 3]);
      o[4] = (float)s;
      o[5] = (float)scid[q];
    }
  }
}

extern "C" void kernel_launch(void* const* d_in, const int* in_sizes, int n_in,
                              void* d_out, int out_size, void* d_ws, size_t ws_size,
                              hipStream_t stream) {
  const int*   x = (const int*)d_in[0];
  const float* W = (const float*)d_in[1];
  double* At  = (double*)d_ws;
  double* Y   = (double*)((char*)d_ws + WS_Y);
  double* sc  = (double*)((char*)d_ws + WS_SC);
  int*    cid = (int*)((char*)d_ws + WS_CID);
  pool_kernel<<<dim3(19200), dim3(256), 0, stream>>>(x, At);
  gemm_kernel<<<dim3(197, NCHUNK), dim3(512), 0, stream>>>(At, W, Y);
  argmax_kernel<<<dim3(4800), dim3(256), 0, stream>>>(Y, sc, cid);
  select_kernel<<<dim3(64), dim3(256), 0, stream>>>(Y, sc, cid, (float*)d_out);
}